// Round 11
// baseline (473.321 us; speedup 1.0000x reference)
//
#include <hip/hip_runtime.h>
#include <math.h>

#define NN 20000
#define NE 320000
#define NB 4096

typedef unsigned short u16;
typedef unsigned char u8;
typedef __attribute__((ext_vector_type(8))) short short8;
typedef __attribute__((ext_vector_type(4))) float f32x4;
typedef __attribute__((ext_vector_type(2))) float f32x2;

#define FP8_SCALE 16.0f
#define FP8_INV 0.0625f
#define LOG2E 1.44269504088896341f

__device__ __forceinline__ float b2f(u16 u) {
  unsigned int x = ((unsigned int)u) << 16;
  return __uint_as_float(x);
}
__device__ __forceinline__ u16 f2b(float f) {
  unsigned int x = __float_as_uint(f);
  return (u16)((x + 0x7fffu + ((x >> 16) & 1u)) >> 16);
}
__device__ __forceinline__ float q2f(u8 b) {
  f32x2 v = __builtin_amdgcn_cvt_pk_f32_fp8((int)b, false);
  return v[0];
}
__device__ __forceinline__ void q4(unsigned int u, float* f) {
  f32x2 lo = __builtin_amdgcn_cvt_pk_f32_fp8((int)u, false);
  f32x2 hi = __builtin_amdgcn_cvt_pk_f32_fp8((int)u, true);
  f[0] = lo[0]; f[1] = lo[1]; f[2] = hi[0]; f[3] = hi[1];
}
template <int CTRL>
__device__ __forceinline__ float dppadd(float x) {
  int y = __builtin_amdgcn_update_dpp(0, __float_as_int(x), CTRL, 0xf, 0xf, true);
  return x + __int_as_float(y);
}
__device__ __forceinline__ float red16(float x) {
  x = dppadd<0xB1>(x);
  x = dppadd<0x4E>(x);
  x = dppadd<0x124>(x);
  x = dppadd<0x128>(x);
  return x;
}

// A-fragment loaders: bf16 passthrough / f32 inline-convert
__device__ __forceinline__ short8 lda8(const u16* p) {
  return *reinterpret_cast<const short8*>(p);
}
__device__ __forceinline__ short8 lda8(const float* p) {
  float4 a = *reinterpret_cast<const float4*>(p);
  float4 b = *reinterpret_cast<const float4*>(p + 4);
  short8 r;
  r[0] = (short)f2b(a.x); r[1] = (short)f2b(a.y);
  r[2] = (short)f2b(a.z); r[3] = (short)f2b(a.w);
  r[4] = (short)f2b(b.x); r[5] = (short)f2b(b.y);
  r[6] = (short)f2b(b.z); r[7] = (short)f2b(b.w);
  return r;
}

// ------------------------------------------------ packing (transposed bf16 weights)

__global__ void k_pack1(const float* __restrict__ w0, const float* __restrict__ w1,
                        const float* __restrict__ w2, const float* __restrict__ w3,
                        const float* __restrict__ w4, const float* __restrict__ b1,
                        const float* __restrict__ b2, const float* __restrict__ b3,
                        const float* __restrict__ b4, u16* __restrict__ Wt,
                        float* __restrict__ bp) {
  int t = blockIdx.x * blockDim.x + threadIdx.x;
  if (t < 1280 * 128) {
    int j = t >> 7, k = t & 127;
    int seg = j >> 8, jj = j & 255;
    const float* s = (seg == 0) ? w0 : (seg == 1) ? w1 : (seg == 2) ? w2 : (seg == 3) ? w3 : w4;
    Wt[t] = f2b(s[k * 256 + jj]);
  }
  if (t < 1280) {
    int seg = t >> 8, jj = t & 255;
    bp[t] = (seg == 0) ? 0.0f : (seg == 1) ? b1[jj] : (seg == 2) ? b2[jj] : (seg == 3) ? b3[jj] : b4[jj];
  }
}

__global__ void k_pack2(const float* __restrict__ wq, const float* __restrict__ wk,
                        const float* __restrict__ wv, const float* __restrict__ ws,
                        const float* __restrict__ wg, const float* __restrict__ bq,
                        const float* __restrict__ bk, const float* __restrict__ bv,
                        const float* __restrict__ bs, u16* __restrict__ Wt,
                        float* __restrict__ bp) {
  int t = blockIdx.x * blockDim.x + threadIdx.x;
  if (t < 160 * 256) {
    int j = t >> 8, k = t & 255;
    int seg = j >> 5, jj = j & 31;
    const float* s = (seg == 0) ? wq : (seg == 1) ? wk : (seg == 2) ? wv : (seg == 3) ? ws : wg;
    Wt[t] = f2b(s[k * 32 + jj]);
  }
  if (t < 160) {
    int seg = t >> 5, jj = t & 31;
    bp[t] = (seg == 0) ? bq[jj] : (seg == 1) ? bk[jj] : (seg == 2) ? bv[jj] : (seg == 3) ? bs[jj] : 0.0f;
  }
}

// ------------------------------------------------ CSR build

__global__ void k_hist(const int* __restrict__ dst, int* __restrict__ deg) {
  int t = blockIdx.x * blockDim.x + threadIdx.x;
  if (t < NE) atomicAdd(&deg[dst[t]], 1);
}

__global__ void k_scan20000(const int* __restrict__ deg, int* __restrict__ offs,
                            int* __restrict__ cur) {
  __shared__ int part[1024];
  int t = threadIdx.x;
  int loc[20];
  int s = 0;
#pragma unroll
  for (int i = 0; i < 20; ++i) {
    int idx = t * 20 + i;
    int v = (idx < NN) ? deg[idx] : 0;
    loc[i] = s;
    s += v;
  }
  part[t] = s;
  __syncthreads();
  for (int off = 1; off < 1024; off <<= 1) {
    int v = (t >= off) ? part[t - off] : 0;
    __syncthreads();
    part[t] += v;
    __syncthreads();
  }
  int base = (t > 0) ? part[t - 1] : 0;
#pragma unroll
  for (int i = 0; i < 20; ++i) {
    int idx = t * 20 + i;
    if (idx < NN) {
      offs[idx] = base + loc[i];
      cur[idx] = base + loc[i];
    }
  }
  if (t == 1023) offs[NN] = part[1023];
}

__global__ void k_scatter(const int* __restrict__ src, const int* __restrict__ dst,
                          int* __restrict__ cur, int* __restrict__ esrcs) {
  int t = blockIdx.x * blockDim.x + threadIdx.x;
  if (t >= NE) return;
  int d = dst[t];
  int pos = atomicAdd(&cur[d], 1);
  esrcs[pos] = src[t];
}

// ------------------------------------------------ MFMA GEMM, transposed epilogue,
// fused als/ald dot (GAT attention coefficients computed from f32 pre-quant values).

template <int LAYER, typename TA>
__global__ void k_mfma_gemm_s(const TA* __restrict__ A0, const TA* __restrict__ A1,
                              int asel, const u16* __restrict__ Bt,
                              const float* __restrict__ bias, int M, int K, int Nc,
                              u8* __restrict__ G, u16* __restrict__ Cb,
                              const float* __restrict__ gasrc,
                              const float* __restrict__ gadst,
                              float* __restrict__ als, float* __restrict__ ald) {
  const TA* A = (blockIdx.x >= (unsigned)asel) ? A1 : A0;
  int m0 = blockIdx.y * 128, n0 = blockIdx.x * 128;
  int wid = threadIdx.x >> 6, lane = threadIdx.x & 63;
  int mw = m0 + (wid & 1) * 64, nw = n0 + (wid >> 1) * 64;
  int arow = mw + (lane & 15);
  int bcol = nw + (lane & 15);
  int kblk = (lane >> 4) * 8;
  f32x4 acc[4][4] = {};
  const short8 zero8 = {0, 0, 0, 0, 0, 0, 0, 0};
  for (int k0 = 0; k0 < K; k0 += 32) {
    short8 af[4], bf[4];
#pragma unroll
    for (int mf = 0; mf < 4; ++mf) {
      int r = arow + mf * 16;
      if (r > M - 1) r = M - 1;
      af[mf] = lda8(&A[(size_t)r * K + k0 + kblk]);
    }
#pragma unroll
    for (int nf = 0; nf < 4; ++nf) {
      int c = bcol + nf * 16;
      bf[nf] = (c < Nc) ? *reinterpret_cast<const short8*>(&Bt[(size_t)c * K + k0 + kblk])
                        : zero8;
    }
#pragma unroll
    for (int mf = 0; mf < 4; ++mf)
#pragma unroll
      for (int nf = 0; nf < 4; ++nf)
        acc[mf][nf] = __builtin_amdgcn_mfma_f32_16x16x32_bf16(bf[nf], af[mf],
                                                              acc[mf][nf], 0, 0, 0);
  }
  const int CSTR = (LAYER == 1) ? 512 : 64;
  const int GSTR = (LAYER == 1) ? 768 : 96;
  // does this wave cover GAT-head columns?
  bool alwave = (LAYER == 1) ? (n0 < 256) : (nw == 128);
#pragma unroll
  for (int mf = 0; mf < 4; ++mf) {
    int row = mw + mf * 16 + (lane & 15);
    bool rv = row < M;
    float alsum = 0.0f, aldsum = 0.0f;
#pragma unroll
    for (int nf = 0; nf < 4; ++nf) {
      int col0 = nw + nf * 16 + ((lane >> 4) << 2);
      if (col0 >= Nc) continue;
      float4 bs4 = *reinterpret_cast<const float4*>(&bias[col0]);
      float v0 = acc[mf][nf][0] + bs4.x;
      float v1 = acc[mf][nf][1] + bs4.y;
      float v2 = acc[mf][nf][2] + bs4.z;
      float v3 = acc[mf][nf][3] + bs4.w;
      if (alwave) {
        if (LAYER == 1) {
          alsum += v0 * gasrc[col0] + v1 * gasrc[col0 + 1] + v2 * gasrc[col0 + 2] +
                   v3 * gasrc[col0 + 3];
          aldsum += v0 * gadst[col0] + v1 * gadst[col0 + 1] + v2 * gadst[col0 + 2] +
                    v3 * gadst[col0 + 3];
        } else if (col0 >= 128 && col0 < 160) {
          int c = col0 - 128;
          alsum += v0 * gasrc[c] + v1 * gasrc[c + 1] + v2 * gasrc[c + 2] + v3 * gasrc[c + 3];
          aldsum += v0 * gadst[c] + v1 * gadst[c + 1] + v2 * gadst[c + 2] + v3 * gadst[c + 3];
        }
      }
      if (!rv) continue;
      int seg = (LAYER == 1) ? (col0 >> 8) : (col0 >> 5);
      bool tobf = (LAYER == 1) ? (seg == 1 || seg == 4) : (seg == 0 || seg == 3);
      if (tobf) {
        int ccol = (LAYER == 1) ? ((seg == 1) ? col0 - 256 : col0 - 768)
                                : ((seg == 0) ? col0 : col0 - 64);
        ushort4 w4;
        w4.x = f2b(v0); w4.y = f2b(v1); w4.z = f2b(v2); w4.w = f2b(v3);
        *reinterpret_cast<ushort4*>(&Cb[(size_t)row * CSTR + ccol]) = w4;
      } else {
        int gcol = (LAYER == 1) ? ((seg == 0) ? col0 : col0 - 256)
                                : ((seg == 4) ? col0 - 64 : col0 - 32);
        unsigned int p = (unsigned int)__builtin_amdgcn_cvt_pk_fp8_f32(
            v0 * FP8_SCALE, v1 * FP8_SCALE, 0, false);
        p = (unsigned int)__builtin_amdgcn_cvt_pk_fp8_f32(
            v2 * FP8_SCALE, v3 * FP8_SCALE, (int)p, true);
        *reinterpret_cast<unsigned int*>(&G[(size_t)row * GSTR + gcol]) = p;
      }
    }
    if (alwave) {
      alsum += __shfl_xor(alsum, 16);
      alsum += __shfl_xor(alsum, 32);
      aldsum += __shfl_xor(aldsum, 16);
      aldsum += __shfl_xor(aldsum, 32);
      if (lane < 16 && rv) {
        if (LAYER == 1) {
          int head = nw >> 6;
          als[row * 4 + head] = alsum * LOG2E;
          ald[row * 4 + head] = aldsum * LOG2E;
        } else {
          als[row] = alsum * LOG2E;
          ald[row] = aldsum * LOG2E;
        }
      }
    }
  }
}

// ------------------------------------------------ aggregates (proven r9/r10)

// Layer-1 FUSED aggregate: TWO waves per dst (edges at stride 2), LDS combine.
__global__ void k_agg256_fused(const int* __restrict__ offs, const int* __restrict__ esrcs,
                               const float* __restrict__ als, const float* __restrict__ ald,
                               const u8* __restrict__ G8, const u16* __restrict__ C1b,
                               const float* __restrict__ gbias,
                               const float* __restrict__ pg, const float* __restrict__ pt,
                               u16* __restrict__ outG, u16* __restrict__ outT) {
  __shared__ float part[2][64][10];
  int g = threadIdx.x >> 6;
  int dl = g >> 1, half = g & 1;
  int d = blockIdx.x * 2 + dl;
  int lane = threadIdx.x & 63;
  int head = lane >> 4, c4 = lane << 2;
  ushort4 q4v = *reinterpret_cast<const ushort4*>(&C1b[(size_t)d * 512 + c4]);
  float q0 = b2f(q4v.x), q1 = b2f(q4v.y), q2 = b2f(q4v.z), q3 = b2f(q4v.w);
  float aldd = ald[d * 4 + head];
  float ga0 = 0, ga1 = 0, ga2 = 0, ga3 = 0, gden = 0.0f;
  float ta0 = 0, ta1 = 0, ta2 = 0, ta3 = 0;
  float tden = half ? 0.0f : 1e-16f;
  int bs = offs[d] + half, be = offs[d + 1];
  const float GTC = 0.125f * FP8_INV * LOG2E;
  unsigned int f0 = 0, k0 = 0, v0 = 0, f1 = 0, k1 = 0, v1 = 0;
  float al0 = 0.0f, al1 = 0.0f;
  if (bs < be) {
    int s = esrcs[bs];
    const u8* row = &G8[(size_t)s * 768];
    f0 = *reinterpret_cast<const unsigned int*>(&row[c4]);
    k0 = *reinterpret_cast<const unsigned int*>(&row[256 + c4]);
    v0 = *reinterpret_cast<const unsigned int*>(&row[512 + c4]);
    al0 = als[s * 4 + head];
  }
  if (bs + 2 < be) {
    int s = esrcs[bs + 2];
    const u8* row = &G8[(size_t)s * 768];
    f1 = *reinterpret_cast<const unsigned int*>(&row[c4]);
    k1 = *reinterpret_cast<const unsigned int*>(&row[256 + c4]);
    v1 = *reinterpret_cast<const unsigned int*>(&row[512 + c4]);
    al1 = als[s * 4 + head];
  }
  for (int i = bs; i < be; i += 2) {
    unsigned int f2_ = 0, k2_ = 0, v2_ = 0;
    float al2_ = 0.0f;
    if (i + 4 < be) {
      int s = esrcs[i + 4];
      const u8* row = &G8[(size_t)s * 768];
      f2_ = *reinterpret_cast<const unsigned int*>(&row[c4]);
      k2_ = *reinterpret_cast<const unsigned int*>(&row[256 + c4]);
      v2_ = *reinterpret_cast<const unsigned int*>(&row[512 + c4]);
      al2_ = als[s * 4 + head];
    }
    float kf[4];
    q4(k0, kf);
    float pp = q0 * kf[0];
    pp = fmaf(q1, kf[1], pp);
    pp = fmaf(q2, kf[2], pp);
    pp = fmaf(q3, kf[3], pp);
    pp = red16(pp);
    float pet = exp2f(pp * GTC);
    float v = al0 + aldd;
    float peg = exp2f(v >= 0.0f ? v : 0.2f * v);
    float ff[4], vf[4];
    q4(f0, ff);
    q4(v0, vf);
    ga0 = fmaf(peg, ff[0], ga0);
    ga1 = fmaf(peg, ff[1], ga1);
    ga2 = fmaf(peg, ff[2], ga2);
    ga3 = fmaf(peg, ff[3], ga3);
    gden += peg;
    ta0 = fmaf(pet, vf[0], ta0);
    ta1 = fmaf(pet, vf[1], ta1);
    ta2 = fmaf(pet, vf[2], ta2);
    ta3 = fmaf(pet, vf[3], ta3);
    tden += pet;
    f0 = f1; k0 = k1; v0 = v1; al0 = al1;
    f1 = f2_; k1 = k2_; v1 = v2_; al1 = al2_;
  }
  if (half == 0) {  // self loop on wave 0
    float v = als[d * 4 + head] + aldd;
    float pe = exp2f(v >= 0.0f ? v : 0.2f * v);
    float ff[4];
    q4(*reinterpret_cast<const unsigned int*>(&G8[(size_t)d * 768 + c4]), ff);
    ga0 = fmaf(pe, ff[0], ga0);
    ga1 = fmaf(pe, ff[1], ga1);
    ga2 = fmaf(pe, ff[2], ga2);
    ga3 = fmaf(pe, ff[3], ga3);
    gden += pe;
  }
  if (half == 1) {
    float* p = part[dl][lane];
    p[0] = ga0; p[1] = ga1; p[2] = ga2; p[3] = ga3; p[4] = gden;
    p[5] = ta0; p[6] = ta1; p[7] = ta2; p[8] = ta3; p[9] = tden;
  }
  __syncthreads();
  if (half == 1) return;
  const float* p = part[dl][lane];
  ga0 += p[0]; ga1 += p[1]; ga2 += p[2]; ga3 += p[3]; gden += p[4];
  ta0 += p[5]; ta1 += p[6]; ta2 += p[7]; ta3 += p[8]; tden += p[9];
  float ig = FP8_INV / gden, it = FP8_INV / tden;
  float o0 = ga0 * ig + gbias[c4 + 0];
  float o1 = ga1 * ig + gbias[c4 + 1];
  float o2 = ga2 * ig + gbias[c4 + 2];
  float o3 = ga3 * ig + gbias[c4 + 3];
  o0 = o0 >= 0.0f ? o0 : pg[c4 + 0] * o0;
  o1 = o1 >= 0.0f ? o1 : pg[c4 + 1] * o1;
  o2 = o2 >= 0.0f ? o2 : pg[c4 + 2] * o2;
  o3 = o3 >= 0.0f ? o3 : pg[c4 + 3] * o3;
  ushort4 wg4;
  wg4.x = f2b(o0); wg4.y = f2b(o1); wg4.z = f2b(o2); wg4.w = f2b(o3);
  *reinterpret_cast<ushort4*>(&outG[(size_t)d * 256 + c4]) = wg4;
  ushort4 sk = *reinterpret_cast<const ushort4*>(&C1b[(size_t)d * 512 + 256 + c4]);
  float u0 = ta0 * it + b2f(sk.x);
  float u1 = ta1 * it + b2f(sk.y);
  float u2 = ta2 * it + b2f(sk.z);
  float u3 = ta3 * it + b2f(sk.w);
  u0 = u0 >= 0.0f ? u0 : pt[c4 + 0] * u0;
  u1 = u1 >= 0.0f ? u1 : pt[c4 + 1] * u1;
  u2 = u2 >= 0.0f ? u2 : pt[c4 + 2] * u2;
  u3 = u3 >= 0.0f ? u3 : pt[c4 + 3] * u3;
  ushort4 wt4;
  wt4.x = f2b(u0); wt4.y = f2b(u1); wt4.z = f2b(u2); wt4.w = f2b(u3);
  *reinterpret_cast<ushort4*>(&outT[(size_t)d * 256 + c4]) = wt4;
}

// Layer-2 FUSED aggregate + fuse_w matmul + column-sum accumulation.
__global__ void k_agg32_fuse(const int* __restrict__ offs, const int* __restrict__ esrcs,
                             const float* __restrict__ als, const float* __restrict__ ald,
                             const u8* __restrict__ G28, const u16* __restrict__ C2b,
                             const float* __restrict__ gbias,
                             const float* __restrict__ pg, const float* __restrict__ pt,
                             const float* __restrict__ fw, const float* __restrict__ fb,
                             float* __restrict__ x2out, float* __restrict__ colsum) {
  __shared__ float xgv[8][32], xtv[8][32];
  int g = threadIdx.x >> 5, l = threadIdx.x & 31;
  int d = blockIdx.x * 8 + g;
  float qv = b2f(C2b[(size_t)d * 64 + l]);
  float aldd = ald[d];
  float ga = 0.0f, gden = 0.0f;
  float ta = 0.0f, tden = 1e-16f;
  int b0 = offs[d], b1 = offs[d + 1];
  const float GTC2 = 0.17677669529663687f * FP8_INV * LOG2E;
  u8 kc = 0, vc = 0, hc = 0;
  float alc = 0;
  if (b0 < b1) {
    int sc = esrcs[b0];
    const u8* row = &G28[(size_t)sc * 96];
    kc = row[l]; vc = row[32 + l]; hc = row[64 + l];
    alc = als[sc];
  }
  for (int i = b0; i < b1; ++i) {
    u8 kn = kc, vn = vc, hn = hc;
    float aln = alc;
    if (i + 1 < b1) {
      int sn = esrcs[i + 1];
      const u8* row = &G28[(size_t)sn * 96];
      kn = row[l]; vn = row[32 + l]; hn = row[64 + l];
      aln = als[sn];
    }
    float pp = qv * q2f(kc);
    pp = red16(pp);
    pp += __shfl_xor(pp, 16, 32);
    float pet = exp2f(pp * GTC2);
    float v = alc + aldd;
    float peg = exp2f(v >= 0.0f ? v : 0.2f * v);
    ga = fmaf(peg, q2f(hc), ga);
    gden += peg;
    ta = fmaf(pet, q2f(vc), ta);
    tden += pet;
    kc = kn; vc = vn; hc = hn; alc = aln;
  }
  {
    float v = als[d] + aldd;
    float pe = exp2f(v >= 0.0f ? v : 0.2f * v);
    ga = fmaf(pe, q2f(G28[(size_t)d * 96 + 64 + l]), ga);
    gden += pe;
  }
  float og = ga * FP8_INV / gden + gbias[l];
  og = og >= 0.0f ? og : pg[l] * og;
  float ot = ta * FP8_INV / tden + b2f(C2b[(size_t)d * 64 + 32 + l]);
  ot = ot >= 0.0f ? ot : pt[l] * ot;
  xgv[g][l] = og;
  xtv[g][l] = ot;
  __syncthreads();
  float acc = fb[l];
#pragma unroll
  for (int i = 0; i < 32; ++i) {
    acc = fmaf(xgv[g][i], fw[i * 32 + l], acc);
    acc = fmaf(xtv[g][i], fw[(32 + i) * 32 + l], acc);
  }
  x2out[(size_t)d * 32 + l] = acc;
  __syncthreads();
  xgv[g][l] = acc;
  __syncthreads();
  if (g == 0) {
    float s = acc;
#pragma unroll
    for (int i = 1; i < 8; ++i) s += xgv[i][l];
    atomicAdd(&colsum[(blockIdx.x & 7) * 32 + l], s);
  }
}

// ------------------------------------------------ epilogue

__global__ void k_disc_all(const float* __restrict__ x2o, const float* __restrict__ x2a_,
                           const float* __restrict__ cso, const float* __restrict__ csa,
                           const float* __restrict__ mlp_w, const float* __restrict__ mlp_b,
                           const float* __restrict__ disc_w, const float* __restrict__ db,
                           const float* __restrict__ aw, const float* __restrict__ ab,
                           float* __restrict__ ret_os, float* __restrict__ ret_os_a,
                           float* __restrict__ logits) {
  __shared__ float sgv[64], h1s[32], h2s[32], m1[32], m2[32], sadv[33];
  int t = threadIdx.x;
  if (t < 64) {
    int j = t & 31;
    const float* cs = (t < 32) ? cso : csa;
    float m = 0.0f;
#pragma unroll
    for (int i = 0; i < 8; ++i) m += cs[i * 32 + j];
    sgv[t] = 1.0f / (1.0f + expf(-m / (float)NN));
  }
  if (t >= 64 && t < 96) {
    int j = t & 31;
    float s = 0.0f;
#pragma unroll
    for (int i = 0; i < 32; ++i) s += aw[j * 32 + i];
    sadv[j] = s;
  } else if (t == 96) {
    float s = 0.0f;
#pragma unroll
    for (int i = 0; i < 32; ++i) s += ab[i];
    sadv[32] = s;
  }
  __syncthreads();
  if (t < 64) {
    int j = t & 31;
    const float* sg = (t < 32) ? sgv : sgv + 32;
    float acc = mlp_b[j];
#pragma unroll
    for (int i = 0; i < 32; ++i) acc = fmaf(sg[i], mlp_w[i * 32 + j], acc);
    (t < 32 ? h1s : h2s)[j] = acc;
  }
  __syncthreads();
  if (t < 64) {
    int k = t & 31;
    const float* hv = (t < 32) ? h1s : h2s;
    float acc = 0.0f;
#pragma unroll
    for (int i = 0; i < 32; ++i) acc = fmaf(disc_w[k * 32 + i], hv[i], acc);
    (t < 32 ? m1 : m2)[k] = acc;
  }
  __syncthreads();
  int n = blockIdx.x * blockDim.x + t;
  if (n >= NN) return;
  const float* a = x2o + (size_t)n * 32;
  const float* b = x2a_ + (size_t)n * 32;
  float s_oo = 0, s_ao = 0, s_aa = 0, s_oa = 0;
  float lo = sadv[32], la = sadv[32];
#pragma unroll
  for (int i = 0; i < 32; ++i) {
    float v1 = m1[i], v2 = m2[i], av = sadv[i];
    float ai = a[i], bi = b[i];
    s_oo = fmaf(ai, v1, s_oo);
    s_ao = fmaf(bi, v1, s_ao);
    s_aa = fmaf(bi, v2, s_aa);
    s_oa = fmaf(ai, v2, s_oa);
    lo = fmaf(ai, av, lo);
    la = fmaf(bi, av, la);
  }
  float bb = db[0];
  ret_os[n * 2 + 0] = s_oo + bb;
  ret_os[n * 2 + 1] = s_ao + bb;
  ret_os_a[n * 2 + 0] = s_aa + bb;
  ret_os_a[n * 2 + 1] = s_oa + bb;
  logits[n] = lo;
  logits[NN + n] = la;
}

__global__ void k_dec(const float* __restrict__ x2o, const int* __restrict__ idx0,
                      const int* __restrict__ idx1, const float* __restrict__ w1,
                      const float* __restrict__ b1, const float* __restrict__ w2,
                      const float* __restrict__ b2, const float* __restrict__ w3,
                      const float* __restrict__ b3, float* __restrict__ logo,
                      float* __restrict__ log1) {
  __shared__ float hhs[512];
  int bb = blockIdx.x;
  const float* r0 = x2o + (size_t)idx0[bb] * 32;
  const float* r1 = x2o + (size_t)idx1[bb] * 32;
  int t = threadIdx.x;
  for (int n = t; n < 512; n += 256) {
    float acc = b1[n];
#pragma unroll
    for (int i = 0; i < 32; ++i) {
      acc = fmaf(r0[i], w1[i * 512 + n], acc);
      acc = fmaf(r1[i], w1[(32 + i) * 512 + n], acc);
    }
    hhs[n] = fmaxf(acc, 0.0f);
  }
  __syncthreads();
  int g = t >> 6, lane = t & 63;
  const float* ws = (g < 2) ? w2 : w3;
  int jj = g & 1;
  float acc = 0.0f;
#pragma unroll
  for (int k = 0; k < 8; ++k) acc = fmaf(hhs[lane + k * 64], ws[(lane + k * 64) * 2 + jj], acc);
  acc += __shfl_xor(acc, 32);
  acc += __shfl_xor(acc, 16);
  acc += __shfl_xor(acc, 8);
  acc += __shfl_xor(acc, 4);
  acc += __shfl_xor(acc, 2);
  acc += __shfl_xor(acc, 1);
  if (lane == 0) {
    float b = (g < 2) ? b2[jj] : b3[jj];
    ((g < 2) ? logo : log1)[bb * 2 + jj] = acc + b;
  }
}

// ------------------------------------------------ host

extern "C" void kernel_launch(void* const* d_in, const int* in_sizes, int n_in,
                              void* d_out, int out_size, void* d_ws, size_t ws_size,
                              hipStream_t stream) {
  const float* x_o = (const float*)d_in[0];
  const float* x_a = (const float*)d_in[1];
  const float* gat1_w = (const float*)d_in[2];
  const float* gat1_asrc = (const float*)d_in[3];
  const float* gat1_adst = (const float*)d_in[4];
  const float* gat1_b = (const float*)d_in[5];
  const float* gat2_w = (const float*)d_in[6];
  const float* gat2_asrc = (const float*)d_in[7];
  const float* gat2_adst = (const float*)d_in[8];
  const float* gat2_b = (const float*)d_in[9];
  const float* pg1 = (const float*)d_in[10];
  const float* pg2 = (const float*)d_in[11];
  const float* gt1_wq = (const float*)d_in[12];
  const float* gt1_bq = (const float*)d_in[13];
  const float* gt1_wk = (const float*)d_in[14];
  const float* gt1_bk = (const float*)d_in[15];
  const float* gt1_wv = (const float*)d_in[16];
  const float* gt1_bv = (const float*)d_in[17];
  const float* gt1_ws = (const float*)d_in[18];
  const float* gt1_bs = (const float*)d_in[19];
  const float* gt2_wq = (const float*)d_in[20];
  const float* gt2_bq = (const float*)d_in[21];
  const float* gt2_wk = (const float*)d_in[22];
  const float* gt2_bk = (const float*)d_in[23];
  const float* gt2_wv = (const float*)d_in[24];
  const float* gt2_bv = (const float*)d_in[25];
  const float* gt2_ws = (const float*)d_in[26];
  const float* gt2_bs = (const float*)d_in[27];
  const float* pt1 = (const float*)d_in[28];
  const float* pt2 = (const float*)d_in[29];
  const float* fuse_w = (const float*)d_in[30];
  const float* fuse_b = (const float*)d_in[31];
  const float* mlp1_w = (const float*)d_in[32];
  const float* mlp1_b = (const float*)d_in[33];
  const float* disc_w = (const float*)d_in[34];
  const float* disc_b = (const float*)d_in[35];
  const float* fus_w1 = (const float*)d_in[36];
  const float* fus_b1 = (const float*)d_in[37];
  const float* fus_w2 = (const float*)d_in[38];
  const float* fus_b2 = (const float*)d_in[39];
  const float* fus_w3 = (const float*)d_in[40];
  const float* fus_b3 = (const float*)d_in[41];
  const float* adv_w = (const float*)d_in[42];
  const float* adv_b = (const float*)d_in[43];
  const int* ei = (const int*)d_in[44];
  const int* idxp = (const int*)d_in[45];
  const int* esrc = ei;
  const int* edst = ei + NE;
  const int* idx0 = idxp;
  const int* idx1 = idxp + NB;

  // ---- workspace carve (float units) ----
  float* w = (float*)d_ws;
  size_t o = 0;
  u8* G8 = (u8*)(w + o); o += 3840000;               // 20000*768 fp8
  u16* C1b = (u16*)(w + o); o += 5120000;            // 20000*512 bf16
  u8* G28 = (u8*)(w + o); o += 480000;               // 20000*96 fp8
  u16* C2b = (u16*)(w + o); o += 640000;             // 20000*64 bf16
  u16* bufB = (u16*)(w + o); o += 2560000;           // 20000*256 bf16
  u16* bufE = (u16*)(w + o); o += 2560000;           // 20000*256 bf16
  u16* Wt1 = (u16*)(w + o); o += 81920;              // 1280*128 bf16
  u16* Wt2 = (u16*)(w + o); o += 20480;              // 160*256 bf16
  float* bp1 = w + o; o += 1280;
  float* bp2 = w + o; o += 160;
  float* als = w + o; o += NN * 4;
  float* ald = w + o; o += NN * 4;
  float* x2a = w + o; o += NN * 32;
  int* deg = (int*)(w + o); o += NN;
  int* offs = (int*)(w + o); o += NN + 8;
  int* cur = (int*)(w + o); o += NN;
  int* esrcs = (int*)(w + o); o += NE;
  float* colsum_o = w + o; o += 256;   // 8 shadows x 32
  float* colsum_a = w + o; o += 256;

  float* out = (float*)d_out;
  float* out_log = out;               // [B,2]
  float* out_ret = out + 8192;        // [N,2]
  float* out_reta = out + 48192;      // [N,2]
  float* out_x2o = out + 88192;       // [N,32]
  float* out_logit = out + 728192;    // [1,2N]
  float* out_log1 = out + 768192;     // [B,2]

  // ---- weight packing ----
  k_pack1<<<(1280 * 128 + 255) / 256, 256, 0, stream>>>(gat1_w, gt1_wq, gt1_wk, gt1_wv,
                                                        gt1_ws, gt1_bq, gt1_bk, gt1_bv,
                                                        gt1_bs, Wt1, bp1);
  k_pack2<<<(160 * 256 + 255) / 256, 256, 0, stream>>>(gt2_wq, gt2_wk, gt2_wv, gt2_ws,
                                                       gat2_w, gt2_bq, gt2_bk, gt2_bv,
                                                       gt2_bs, Wt2, bp2);
  // ---- CSR build + colsum zero ----
  hipMemsetAsync(deg, 0, NN * sizeof(int), stream);
  hipMemsetAsync(colsum_o, 0, 512 * sizeof(float), stream);
  k_hist<<<(NE + 255) / 256, 256, 0, stream>>>(edst, deg);
  k_scan20000<<<1, 1024, 0, stream>>>(deg, offs, cur);
  k_scatter<<<(NE + 255) / 256, 256, 0, stream>>>(esrc, edst, cur, esrcs);

  auto branch = [&](const float* x, float* x2out, float* colsum) {
    // layer 1: MFMA GEMM (f32 A inline-cvt) + fused als/ald epilogue
    {
      dim3 g(10, (NN + 127) / 128);
      k_mfma_gemm_s<1, float><<<g, 256, 0, stream>>>(x, x, 999, Wt1, bp1, NN, 128, 1280,
                                                     G8, C1b, gat1_asrc, gat1_adst,
                                                     als, ald);
    }
    k_agg256_fused<<<NN / 2, 256, 0, stream>>>(offs, esrcs, als, ald, G8, C1b,
                                               gat1_b, pg1, pt1, bufB, bufE);
    // layer 2: MFMA GEMM (bf16 A) + fused als/ald epilogue
    {
      dim3 g(2, (NN + 127) / 128);
      k_mfma_gemm_s<2, u16><<<g, 256, 0, stream>>>(bufE, bufB, 1, Wt2, bp2, NN, 256, 160,
                                                   G28, C2b, gat2_asrc, gat2_adst,
                                                   als, ald);
    }
    k_agg32_fuse<<<NN / 8, 256, 0, stream>>>(offs, esrcs, als, ald, G28, C2b,
                                             gat2_b, pg2, pt2, fuse_w, fuse_b,
                                             x2out, colsum);
  };

  branch(x_o, out_x2o, colsum_o);
  branch(x_a, x2a, colsum_a);

  // ---- summary + discriminator + adversarial (fused) ----
  k_disc_all<<<(NN + 255) / 256, 256, 0, stream>>>(out_x2o, x2a, colsum_o, colsum_a,
                                                   mlp1_w, mlp1_b, disc_w, disc_b,
                                                   adv_w, adv_b, out_ret, out_reta,
                                                   out_logit);
  // ---- decoder (dec1+dec2 fused) ----
  k_dec<<<NB, 256, 0, stream>>>(out_x2o, idx0, idx1, fus_w1, fus_b1, fus_w2, fus_b2,
                                fus_w3, fus_b3, out_log, out_log1);
}

// Round 12
// 422.342 us; speedup vs baseline: 1.1207x; 1.1207x over previous
//
#include <hip/hip_runtime.h>
#include <math.h>

#define NN 20000
#define NE 320000
#define NB 4096

typedef unsigned short u16;
typedef unsigned char u8;
typedef __attribute__((ext_vector_type(8))) short short8;
typedef __attribute__((ext_vector_type(4))) float f32x4;
typedef __attribute__((ext_vector_type(2))) float f32x2;

#define FP8_SCALE 16.0f
#define FP8_INV 0.0625f
#define LOG2E 1.44269504088896341f

__device__ __forceinline__ float b2f(u16 u) {
  unsigned int x = ((unsigned int)u) << 16;
  return __uint_as_float(x);
}
__device__ __forceinline__ u16 f2b(float f) {
  unsigned int x = __float_as_uint(f);
  return (u16)((x + 0x7fffu + ((x >> 16) & 1u)) >> 16);
}
__device__ __forceinline__ float q2f(u8 b) {
  f32x2 v = __builtin_amdgcn_cvt_pk_f32_fp8((int)b, false);
  return v[0];
}
__device__ __forceinline__ void q4(unsigned int u, float* f) {
  f32x2 lo = __builtin_amdgcn_cvt_pk_f32_fp8((int)u, false);
  f32x2 hi = __builtin_amdgcn_cvt_pk_f32_fp8((int)u, true);
  f[0] = lo[0]; f[1] = lo[1]; f[2] = hi[0]; f[3] = hi[1];
}
template <int CTRL>
__device__ __forceinline__ float dppadd(float x) {
  int y = __builtin_amdgcn_update_dpp(0, __float_as_int(x), CTRL, 0xf, 0xf, true);
  return x + __int_as_float(y);
}
__device__ __forceinline__ float red16(float x) {
  x = dppadd<0xB1>(x);
  x = dppadd<0x4E>(x);
  x = dppadd<0x124>(x);
  x = dppadd<0x128>(x);
  return x;
}

// ------------------------------------------------ packing (transposed bf16 weights)

__global__ void k_pack1(const float* __restrict__ w0, const float* __restrict__ w1,
                        const float* __restrict__ w2, const float* __restrict__ w3,
                        const float* __restrict__ w4, const float* __restrict__ b1,
                        const float* __restrict__ b2, const float* __restrict__ b3,
                        const float* __restrict__ b4, u16* __restrict__ Wt,
                        float* __restrict__ bp) {
  int t = blockIdx.x * blockDim.x + threadIdx.x;
  if (t < 1280 * 128) {
    int j = t >> 7, k = t & 127;
    int seg = j >> 8, jj = j & 255;
    const float* s = (seg == 0) ? w0 : (seg == 1) ? w1 : (seg == 2) ? w2 : (seg == 3) ? w3 : w4;
    Wt[t] = f2b(s[k * 256 + jj]);
  }
  if (t < 1280) {
    int seg = t >> 8, jj = t & 255;
    bp[t] = (seg == 0) ? 0.0f : (seg == 1) ? b1[jj] : (seg == 2) ? b2[jj] : (seg == 3) ? b3[jj] : b4[jj];
  }
}

__global__ void k_pack2(const float* __restrict__ wq, const float* __restrict__ wk,
                        const float* __restrict__ wv, const float* __restrict__ ws,
                        const float* __restrict__ wg, const float* __restrict__ bq,
                        const float* __restrict__ bk, const float* __restrict__ bv,
                        const float* __restrict__ bs, u16* __restrict__ Wt,
                        float* __restrict__ bp) {
  int t = blockIdx.x * blockDim.x + threadIdx.x;
  if (t < 160 * 256) {
    int j = t >> 8, k = t & 255;
    int seg = j >> 5, jj = j & 31;
    const float* s = (seg == 0) ? wq : (seg == 1) ? wk : (seg == 2) ? wv : (seg == 3) ? ws : wg;
    Wt[t] = f2b(s[k * 32 + jj]);
  }
  if (t < 160) {
    int seg = t >> 5, jj = t & 31;
    bp[t] = (seg == 0) ? bq[jj] : (seg == 1) ? bk[jj] : (seg == 2) ? bv[jj] : (seg == 3) ? bs[jj] : 0.0f;
  }
}

// both inputs in one launch
__global__ void k_tobf16x2(const float* __restrict__ xo, const float* __restrict__ xa,
                           u16* __restrict__ bo, u16* __restrict__ ba) {
  int t = blockIdx.x * blockDim.x + threadIdx.x;
  if (t >= 2 * NN * 128) return;
  if (t < NN * 128) bo[t] = f2b(xo[t]);
  else ba[t - NN * 128] = f2b(xa[t - NN * 128]);
}

// ------------------------------------------------ CSR build

__global__ void k_hist(const int* __restrict__ dst, int* __restrict__ deg) {
  int t = blockIdx.x * blockDim.x + threadIdx.x;
  if (t < NE) atomicAdd(&deg[dst[t]], 1);
}

__global__ void k_scan20000(const int* __restrict__ deg, int* __restrict__ offs,
                            int* __restrict__ cur) {
  __shared__ int part[1024];
  int t = threadIdx.x;
  int loc[20];
  int s = 0;
#pragma unroll
  for (int i = 0; i < 20; ++i) {
    int idx = t * 20 + i;
    int v = (idx < NN) ? deg[idx] : 0;
    loc[i] = s;
    s += v;
  }
  part[t] = s;
  __syncthreads();
  for (int off = 1; off < 1024; off <<= 1) {
    int v = (t >= off) ? part[t - off] : 0;
    __syncthreads();
    part[t] += v;
    __syncthreads();
  }
  int base = (t > 0) ? part[t - 1] : 0;
#pragma unroll
  for (int i = 0; i < 20; ++i) {
    int idx = t * 20 + i;
    if (idx < NN) {
      offs[idx] = base + loc[i];
      cur[idx] = base + loc[i];
    }
  }
  if (t == 1023) offs[NN] = part[1023];
}

__global__ void k_scatter(const int* __restrict__ src, const int* __restrict__ dst,
                          int* __restrict__ cur, int* __restrict__ esrcs) {
  int t = blockIdx.x * blockDim.x + threadIdx.x;
  if (t >= NE) return;
  int d = dst[t];
  int pos = atomicAdd(&cur[d], 1);
  esrcs[pos] = src[t];
}

// ------------------------------------------------ MFMA GEMM, transposed epilogue,
// fused als/ald dot (bf16 A input — r11's f32-inline-cvt regressed 3x).

template <int LAYER>
__global__ void k_mfma_gemm_s(const u16* __restrict__ A0, const u16* __restrict__ A1,
                              int asel, const u16* __restrict__ Bt,
                              const float* __restrict__ bias, int M, int K, int Nc,
                              u8* __restrict__ G, u16* __restrict__ Cb,
                              const float* __restrict__ gasrc,
                              const float* __restrict__ gadst,
                              float* __restrict__ als, float* __restrict__ ald) {
  const u16* A = (blockIdx.x >= (unsigned)asel) ? A1 : A0;
  int m0 = blockIdx.y * 128, n0 = blockIdx.x * 128;
  int wid = threadIdx.x >> 6, lane = threadIdx.x & 63;
  int mw = m0 + (wid & 1) * 64, nw = n0 + (wid >> 1) * 64;
  int arow = mw + (lane & 15);
  int bcol = nw + (lane & 15);
  int kblk = (lane >> 4) * 8;
  f32x4 acc[4][4] = {};
  const short8 zero8 = {0, 0, 0, 0, 0, 0, 0, 0};
  for (int k0 = 0; k0 < K; k0 += 32) {
    short8 af[4], bf[4];
#pragma unroll
    for (int mf = 0; mf < 4; ++mf) {
      int r = arow + mf * 16;
      if (r > M - 1) r = M - 1;
      af[mf] = *reinterpret_cast<const short8*>(&A[(size_t)r * K + k0 + kblk]);
    }
#pragma unroll
    for (int nf = 0; nf < 4; ++nf) {
      int c = bcol + nf * 16;
      bf[nf] = (c < Nc) ? *reinterpret_cast<const short8*>(&Bt[(size_t)c * K + k0 + kblk])
                        : zero8;
    }
#pragma unroll
    for (int mf = 0; mf < 4; ++mf)
#pragma unroll
      for (int nf = 0; nf < 4; ++nf)
        acc[mf][nf] = __builtin_amdgcn_mfma_f32_16x16x32_bf16(bf[nf], af[mf],
                                                              acc[mf][nf], 0, 0, 0);
  }
  const int CSTR = (LAYER == 1) ? 512 : 64;
  const int GSTR = (LAYER == 1) ? 768 : 96;
  bool alwave = (LAYER == 1) ? (n0 < 256) : (nw == 128);
#pragma unroll
  for (int mf = 0; mf < 4; ++mf) {
    int row = mw + mf * 16 + (lane & 15);
    bool rv = row < M;
    float alsum = 0.0f, aldsum = 0.0f;
#pragma unroll
    for (int nf = 0; nf < 4; ++nf) {
      int col0 = nw + nf * 16 + ((lane >> 4) << 2);
      if (col0 >= Nc) continue;
      float4 bs4 = *reinterpret_cast<const float4*>(&bias[col0]);
      float v0 = acc[mf][nf][0] + bs4.x;
      float v1 = acc[mf][nf][1] + bs4.y;
      float v2 = acc[mf][nf][2] + bs4.z;
      float v3 = acc[mf][nf][3] + bs4.w;
      if (alwave) {
        if (LAYER == 1) {
          alsum += v0 * gasrc[col0] + v1 * gasrc[col0 + 1] + v2 * gasrc[col0 + 2] +
                   v3 * gasrc[col0 + 3];
          aldsum += v0 * gadst[col0] + v1 * gadst[col0 + 1] + v2 * gadst[col0 + 2] +
                    v3 * gadst[col0 + 3];
        } else if (col0 >= 128 && col0 < 160) {
          int c = col0 - 128;
          alsum += v0 * gasrc[c] + v1 * gasrc[c + 1] + v2 * gasrc[c + 2] + v3 * gasrc[c + 3];
          aldsum += v0 * gadst[c] + v1 * gadst[c + 1] + v2 * gadst[c + 2] + v3 * gadst[c + 3];
        }
      }
      if (!rv) continue;
      int seg = (LAYER == 1) ? (col0 >> 8) : (col0 >> 5);
      bool tobf = (LAYER == 1) ? (seg == 1 || seg == 4) : (seg == 0 || seg == 3);
      if (tobf) {
        int ccol = (LAYER == 1) ? ((seg == 1) ? col0 - 256 : col0 - 768)
                                : ((seg == 0) ? col0 : col0 - 64);
        ushort4 w4;
        w4.x = f2b(v0); w4.y = f2b(v1); w4.z = f2b(v2); w4.w = f2b(v3);
        *reinterpret_cast<ushort4*>(&Cb[(size_t)row * CSTR + ccol]) = w4;
      } else {
        int gcol = (LAYER == 1) ? ((seg == 0) ? col0 : col0 - 256)
                                : ((seg == 4) ? col0 - 64 : col0 - 32);
        unsigned int p = (unsigned int)__builtin_amdgcn_cvt_pk_fp8_f32(
            v0 * FP8_SCALE, v1 * FP8_SCALE, 0, false);
        p = (unsigned int)__builtin_amdgcn_cvt_pk_fp8_f32(
            v2 * FP8_SCALE, v3 * FP8_SCALE, (int)p, true);
        *reinterpret_cast<unsigned int*>(&G[(size_t)row * GSTR + gcol]) = p;
      }
    }
    if (alwave) {
      alsum += __shfl_xor(alsum, 16);
      alsum += __shfl_xor(alsum, 32);
      aldsum += __shfl_xor(aldsum, 16);
      aldsum += __shfl_xor(aldsum, 32);
      if (lane < 16 && rv) {
        if (LAYER == 1) {
          int head = nw >> 6;
          als[row * 4 + head] = alsum * LOG2E;
          ald[row * 4 + head] = aldsum * LOG2E;
        } else {
          als[row] = alsum * LOG2E;
          ald[row] = aldsum * LOG2E;
        }
      }
    }
  }
}

// ------------------------------------------------ aggregates (proven r9/r10)

// Layer-1 FUSED aggregate: TWO waves per dst (edges at stride 2), LDS combine.
__global__ void k_agg256_fused(const int* __restrict__ offs, const int* __restrict__ esrcs,
                               const float* __restrict__ als, const float* __restrict__ ald,
                               const u8* __restrict__ G8, const u16* __restrict__ C1b,
                               const float* __restrict__ gbias,
                               const float* __restrict__ pg, const float* __restrict__ pt,
                               u16* __restrict__ outG, u16* __restrict__ outT) {
  __shared__ float part[2][64][10];
  int g = threadIdx.x >> 6;
  int dl = g >> 1, half = g & 1;
  int d = blockIdx.x * 2 + dl;
  int lane = threadIdx.x & 63;
  int head = lane >> 4, c4 = lane << 2;
  ushort4 q4v = *reinterpret_cast<const ushort4*>(&C1b[(size_t)d * 512 + c4]);
  float q0 = b2f(q4v.x), q1 = b2f(q4v.y), q2 = b2f(q4v.z), q3 = b2f(q4v.w);
  float aldd = ald[d * 4 + head];
  float ga0 = 0, ga1 = 0, ga2 = 0, ga3 = 0, gden = 0.0f;
  float ta0 = 0, ta1 = 0, ta2 = 0, ta3 = 0;
  float tden = half ? 0.0f : 1e-16f;
  int bs = offs[d] + half, be = offs[d + 1];
  const float GTC = 0.125f * FP8_INV * LOG2E;
  unsigned int f0 = 0, k0 = 0, v0 = 0, f1 = 0, k1 = 0, v1 = 0;
  float al0 = 0.0f, al1 = 0.0f;
  if (bs < be) {
    int s = esrcs[bs];
    const u8* row = &G8[(size_t)s * 768];
    f0 = *reinterpret_cast<const unsigned int*>(&row[c4]);
    k0 = *reinterpret_cast<const unsigned int*>(&row[256 + c4]);
    v0 = *reinterpret_cast<const unsigned int*>(&row[512 + c4]);
    al0 = als[s * 4 + head];
  }
  if (bs + 2 < be) {
    int s = esrcs[bs + 2];
    const u8* row = &G8[(size_t)s * 768];
    f1 = *reinterpret_cast<const unsigned int*>(&row[c4]);
    k1 = *reinterpret_cast<const unsigned int*>(&row[256 + c4]);
    v1 = *reinterpret_cast<const unsigned int*>(&row[512 + c4]);
    al1 = als[s * 4 + head];
  }
  for (int i = bs; i < be; i += 2) {
    unsigned int f2_ = 0, k2_ = 0, v2_ = 0;
    float al2_ = 0.0f;
    if (i + 4 < be) {
      int s = esrcs[i + 4];
      const u8* row = &G8[(size_t)s * 768];
      f2_ = *reinterpret_cast<const unsigned int*>(&row[c4]);
      k2_ = *reinterpret_cast<const unsigned int*>(&row[256 + c4]);
      v2_ = *reinterpret_cast<const unsigned int*>(&row[512 + c4]);
      al2_ = als[s * 4 + head];
    }
    float kf[4];
    q4(k0, kf);
    float pp = q0 * kf[0];
    pp = fmaf(q1, kf[1], pp);
    pp = fmaf(q2, kf[2], pp);
    pp = fmaf(q3, kf[3], pp);
    pp = red16(pp);
    float pet = exp2f(pp * GTC);
    float v = al0 + aldd;
    float peg = exp2f(v >= 0.0f ? v : 0.2f * v);
    float ff[4], vf[4];
    q4(f0, ff);
    q4(v0, vf);
    ga0 = fmaf(peg, ff[0], ga0);
    ga1 = fmaf(peg, ff[1], ga1);
    ga2 = fmaf(peg, ff[2], ga2);
    ga3 = fmaf(peg, ff[3], ga3);
    gden += peg;
    ta0 = fmaf(pet, vf[0], ta0);
    ta1 = fmaf(pet, vf[1], ta1);
    ta2 = fmaf(pet, vf[2], ta2);
    ta3 = fmaf(pet, vf[3], ta3);
    tden += pet;
    f0 = f1; k0 = k1; v0 = v1; al0 = al1;
    f1 = f2_; k1 = k2_; v1 = v2_; al1 = al2_;
  }
  if (half == 0) {  // self loop on wave 0
    float v = als[d * 4 + head] + aldd;
    float pe = exp2f(v >= 0.0f ? v : 0.2f * v);
    float ff[4];
    q4(*reinterpret_cast<const unsigned int*>(&G8[(size_t)d * 768 + c4]), ff);
    ga0 = fmaf(pe, ff[0], ga0);
    ga1 = fmaf(pe, ff[1], ga1);
    ga2 = fmaf(pe, ff[2], ga2);
    ga3 = fmaf(pe, ff[3], ga3);
    gden += pe;
  }
  if (half == 1) {
    float* p = part[dl][lane];
    p[0] = ga0; p[1] = ga1; p[2] = ga2; p[3] = ga3; p[4] = gden;
    p[5] = ta0; p[6] = ta1; p[7] = ta2; p[8] = ta3; p[9] = tden;
  }
  __syncthreads();
  if (half == 1) return;
  const float* p = part[dl][lane];
  ga0 += p[0]; ga1 += p[1]; ga2 += p[2]; ga3 += p[3]; gden += p[4];
  ta0 += p[5]; ta1 += p[6]; ta2 += p[7]; ta3 += p[8]; tden += p[9];
  float ig = FP8_INV / gden, it = FP8_INV / tden;
  float o0 = ga0 * ig + gbias[c4 + 0];
  float o1 = ga1 * ig + gbias[c4 + 1];
  float o2 = ga2 * ig + gbias[c4 + 2];
  float o3 = ga3 * ig + gbias[c4 + 3];
  o0 = o0 >= 0.0f ? o0 : pg[c4 + 0] * o0;
  o1 = o1 >= 0.0f ? o1 : pg[c4 + 1] * o1;
  o2 = o2 >= 0.0f ? o2 : pg[c4 + 2] * o2;
  o3 = o3 >= 0.0f ? o3 : pg[c4 + 3] * o3;
  ushort4 wg4;
  wg4.x = f2b(o0); wg4.y = f2b(o1); wg4.z = f2b(o2); wg4.w = f2b(o3);
  *reinterpret_cast<ushort4*>(&outG[(size_t)d * 256 + c4]) = wg4;
  ushort4 sk = *reinterpret_cast<const ushort4*>(&C1b[(size_t)d * 512 + 256 + c4]);
  float u0 = ta0 * it + b2f(sk.x);
  float u1 = ta1 * it + b2f(sk.y);
  float u2 = ta2 * it + b2f(sk.z);
  float u3 = ta3 * it + b2f(sk.w);
  u0 = u0 >= 0.0f ? u0 : pt[c4 + 0] * u0;
  u1 = u1 >= 0.0f ? u1 : pt[c4 + 1] * u1;
  u2 = u2 >= 0.0f ? u2 : pt[c4 + 2] * u2;
  u3 = u3 >= 0.0f ? u3 : pt[c4 + 3] * u3;
  ushort4 wt4;
  wt4.x = f2b(u0); wt4.y = f2b(u1); wt4.z = f2b(u2); wt4.w = f2b(u3);
  *reinterpret_cast<ushort4*>(&outT[(size_t)d * 256 + c4]) = wt4;
}

// Layer-2 FUSED aggregate + fuse_w matmul + column-sum accumulation.
__global__ void k_agg32_fuse(const int* __restrict__ offs, const int* __restrict__ esrcs,
                             const float* __restrict__ als, const float* __restrict__ ald,
                             const u8* __restrict__ G28, const u16* __restrict__ C2b,
                             const float* __restrict__ gbias,
                             const float* __restrict__ pg, const float* __restrict__ pt,
                             const float* __restrict__ fw, const float* __restrict__ fb,
                             float* __restrict__ x2out, float* __restrict__ colsum) {
  __shared__ float xgv[8][32], xtv[8][32];
  int g = threadIdx.x >> 5, l = threadIdx.x & 31;
  int d = blockIdx.x * 8 + g;
  float qv = b2f(C2b[(size_t)d * 64 + l]);
  float aldd = ald[d];
  float ga = 0.0f, gden = 0.0f;
  float ta = 0.0f, tden = 1e-16f;
  int b0 = offs[d], b1 = offs[d + 1];
  const float GTC2 = 0.17677669529663687f * FP8_INV * LOG2E;
  u8 kc = 0, vc = 0, hc = 0;
  float alc = 0;
  if (b0 < b1) {
    int sc = esrcs[b0];
    const u8* row = &G28[(size_t)sc * 96];
    kc = row[l]; vc = row[32 + l]; hc = row[64 + l];
    alc = als[sc];
  }
  for (int i = b0; i < b1; ++i) {
    u8 kn = kc, vn = vc, hn = hc;
    float aln = alc;
    if (i + 1 < b1) {
      int sn = esrcs[i + 1];
      const u8* row = &G28[(size_t)sn * 96];
      kn = row[l]; vn = row[32 + l]; hn = row[64 + l];
      aln = als[sn];
    }
    float pp = qv * q2f(kc);
    pp = red16(pp);
    pp += __shfl_xor(pp, 16, 32);
    float pet = exp2f(pp * GTC2);
    float v = alc + aldd;
    float peg = exp2f(v >= 0.0f ? v : 0.2f * v);
    ga = fmaf(peg, q2f(hc), ga);
    gden += peg;
    ta = fmaf(pet, q2f(vc), ta);
    tden += pet;
    kc = kn; vc = vn; hc = hn; alc = aln;
  }
  {
    float v = als[d] + aldd;
    float pe = exp2f(v >= 0.0f ? v : 0.2f * v);
    ga = fmaf(pe, q2f(G28[(size_t)d * 96 + 64 + l]), ga);
    gden += pe;
  }
  float og = ga * FP8_INV / gden + gbias[l];
  og = og >= 0.0f ? og : pg[l] * og;
  float ot = ta * FP8_INV / tden + b2f(C2b[(size_t)d * 64 + 32 + l]);
  ot = ot >= 0.0f ? ot : pt[l] * ot;
  xgv[g][l] = og;
  xtv[g][l] = ot;
  __syncthreads();
  float acc = fb[l];
#pragma unroll
  for (int i = 0; i < 32; ++i) {
    acc = fmaf(xgv[g][i], fw[i * 32 + l], acc);
    acc = fmaf(xtv[g][i], fw[(32 + i) * 32 + l], acc);
  }
  x2out[(size_t)d * 32 + l] = acc;
  __syncthreads();
  xgv[g][l] = acc;
  __syncthreads();
  if (g == 0) {
    float s = acc;
#pragma unroll
    for (int i = 1; i < 8; ++i) s += xgv[i][l];
    atomicAdd(&colsum[(blockIdx.x & 7) * 32 + l], s);
  }
}

// ------------------------------------------------ epilogue

__global__ void k_disc_all(const float* __restrict__ x2o, const float* __restrict__ x2a_,
                           const float* __restrict__ cso, const float* __restrict__ csa,
                           const float* __restrict__ mlp_w, const float* __restrict__ mlp_b,
                           const float* __restrict__ disc_w, const float* __restrict__ db,
                           const float* __restrict__ aw, const float* __restrict__ ab,
                           float* __restrict__ ret_os, float* __restrict__ ret_os_a,
                           float* __restrict__ logits) {
  __shared__ float sgv[64], h1s[32], h2s[32], m1[32], m2[32], sadv[33];
  int t = threadIdx.x;
  if (t < 64) {
    int j = t & 31;
    const float* cs = (t < 32) ? cso : csa;
    float m = 0.0f;
#pragma unroll
    for (int i = 0; i < 8; ++i) m += cs[i * 32 + j];
    sgv[t] = 1.0f / (1.0f + expf(-m / (float)NN));
  }
  if (t >= 64 && t < 96) {
    int j = t & 31;
    float s = 0.0f;
#pragma unroll
    for (int i = 0; i < 32; ++i) s += aw[j * 32 + i];
    sadv[j] = s;
  } else if (t == 96) {
    float s = 0.0f;
#pragma unroll
    for (int i = 0; i < 32; ++i) s += ab[i];
    sadv[32] = s;
  }
  __syncthreads();
  if (t < 64) {
    int j = t & 31;
    const float* sg = (t < 32) ? sgv : sgv + 32;
    float acc = mlp_b[j];
#pragma unroll
    for (int i = 0; i < 32; ++i) acc = fmaf(sg[i], mlp_w[i * 32 + j], acc);
    (t < 32 ? h1s : h2s)[j] = acc;
  }
  __syncthreads();
  if (t < 64) {
    int k = t & 31;
    const float* hv = (t < 32) ? h1s : h2s;
    float acc = 0.0f;
#pragma unroll
    for (int i = 0; i < 32; ++i) acc = fmaf(disc_w[k * 32 + i], hv[i], acc);
    (t < 32 ? m1 : m2)[k] = acc;
  }
  __syncthreads();
  int n = blockIdx.x * blockDim.x + t;
  if (n >= NN) return;
  const float* a = x2o + (size_t)n * 32;
  const float* b = x2a_ + (size_t)n * 32;
  float s_oo = 0, s_ao = 0, s_aa = 0, s_oa = 0;
  float lo = sadv[32], la = sadv[32];
#pragma unroll
  for (int i = 0; i < 32; ++i) {
    float v1 = m1[i], v2 = m2[i], av = sadv[i];
    float ai = a[i], bi = b[i];
    s_oo = fmaf(ai, v1, s_oo);
    s_ao = fmaf(bi, v1, s_ao);
    s_aa = fmaf(bi, v2, s_aa);
    s_oa = fmaf(ai, v2, s_oa);
    lo = fmaf(ai, av, lo);
    la = fmaf(bi, av, la);
  }
  float bb = db[0];
  ret_os[n * 2 + 0] = s_oo + bb;
  ret_os[n * 2 + 1] = s_ao + bb;
  ret_os_a[n * 2 + 0] = s_aa + bb;
  ret_os_a[n * 2 + 1] = s_oa + bb;
  logits[n] = lo;
  logits[NN + n] = la;
}

__global__ void k_dec(const float* __restrict__ x2o, const int* __restrict__ idx0,
                      const int* __restrict__ idx1, const float* __restrict__ w1,
                      const float* __restrict__ b1, const float* __restrict__ w2,
                      const float* __restrict__ b2, const float* __restrict__ w3,
                      const float* __restrict__ b3, float* __restrict__ logo,
                      float* __restrict__ log1) {
  __shared__ float hhs[512];
  int bb = blockIdx.x;
  const float* r0 = x2o + (size_t)idx0[bb] * 32;
  const float* r1 = x2o + (size_t)idx1[bb] * 32;
  int t = threadIdx.x;
  for (int n = t; n < 512; n += 256) {
    float acc = b1[n];
#pragma unroll
    for (int i = 0; i < 32; ++i) {
      acc = fmaf(r0[i], w1[i * 512 + n], acc);
      acc = fmaf(r1[i], w1[(32 + i) * 512 + n], acc);
    }
    hhs[n] = fmaxf(acc, 0.0f);
  }
  __syncthreads();
  int g = t >> 6, lane = t & 63;
  const float* ws = (g < 2) ? w2 : w3;
  int jj = g & 1;
  float acc = 0.0f;
#pragma unroll
  for (int k = 0; k < 8; ++k) acc = fmaf(hhs[lane + k * 64], ws[(lane + k * 64) * 2 + jj], acc);
  acc += __shfl_xor(acc, 32);
  acc += __shfl_xor(acc, 16);
  acc += __shfl_xor(acc, 8);
  acc += __shfl_xor(acc, 4);
  acc += __shfl_xor(acc, 2);
  acc += __shfl_xor(acc, 1);
  if (lane == 0) {
    float b = (g < 2) ? b2[jj] : b3[jj];
    ((g < 2) ? logo : log1)[bb * 2 + jj] = acc + b;
  }
}

// ------------------------------------------------ host

extern "C" void kernel_launch(void* const* d_in, const int* in_sizes, int n_in,
                              void* d_out, int out_size, void* d_ws, size_t ws_size,
                              hipStream_t stream) {
  const float* x_o = (const float*)d_in[0];
  const float* x_a = (const float*)d_in[1];
  const float* gat1_w = (const float*)d_in[2];
  const float* gat1_asrc = (const float*)d_in[3];
  const float* gat1_adst = (const float*)d_in[4];
  const float* gat1_b = (const float*)d_in[5];
  const float* gat2_w = (const float*)d_in[6];
  const float* gat2_asrc = (const float*)d_in[7];
  const float* gat2_adst = (const float*)d_in[8];
  const float* gat2_b = (const float*)d_in[9];
  const float* pg1 = (const float*)d_in[10];
  const float* pg2 = (const float*)d_in[11];
  const float* gt1_wq = (const float*)d_in[12];
  const float* gt1_bq = (const float*)d_in[13];
  const float* gt1_wk = (const float*)d_in[14];
  const float* gt1_bk = (const float*)d_in[15];
  const float* gt1_wv = (const float*)d_in[16];
  const float* gt1_bv = (const float*)d_in[17];
  const float* gt1_ws = (const float*)d_in[18];
  const float* gt1_bs = (const float*)d_in[19];
  const float* gt2_wq = (const float*)d_in[20];
  const float* gt2_bq = (const float*)d_in[21];
  const float* gt2_wk = (const float*)d_in[22];
  const float* gt2_bk = (const float*)d_in[23];
  const float* gt2_wv = (const float*)d_in[24];
  const float* gt2_bv = (const float*)d_in[25];
  const float* gt2_ws = (const float*)d_in[26];
  const float* gt2_bs = (const float*)d_in[27];
  const float* pt1 = (const float*)d_in[28];
  const float* pt2 = (const float*)d_in[29];
  const float* fuse_w = (const float*)d_in[30];
  const float* fuse_b = (const float*)d_in[31];
  const float* mlp1_w = (const float*)d_in[32];
  const float* mlp1_b = (const float*)d_in[33];
  const float* disc_w = (const float*)d_in[34];
  const float* disc_b = (const float*)d_in[35];
  const float* fus_w1 = (const float*)d_in[36];
  const float* fus_b1 = (const float*)d_in[37];
  const float* fus_w2 = (const float*)d_in[38];
  const float* fus_b2 = (const float*)d_in[39];
  const float* fus_w3 = (const float*)d_in[40];
  const float* fus_b3 = (const float*)d_in[41];
  const float* adv_w = (const float*)d_in[42];
  const float* adv_b = (const float*)d_in[43];
  const int* ei = (const int*)d_in[44];
  const int* idxp = (const int*)d_in[45];
  const int* esrc = ei;
  const int* edst = ei + NE;
  const int* idx0 = idxp;
  const int* idx1 = idxp + NB;

  // ---- workspace carve (float units) ----
  float* w = (float*)d_ws;
  size_t o = 0;
  u8* G8 = (u8*)(w + o); o += 3840000;               // 20000*768 fp8
  u16* C1b = (u16*)(w + o); o += 5120000;            // 20000*512 bf16
  u8* G28 = (u8*)(w + o); o += 480000;               // 20000*96 fp8
  u16* C2b = (u16*)(w + o); o += 640000;             // 20000*64 bf16
  u16* bufB = (u16*)(w + o); o += 2560000;           // 20000*256 bf16
  u16* bufE = (u16*)(w + o); o += 2560000;           // 20000*256 bf16
  u16* xb_o = (u16*)(w + o); o += 1280000;           // 20000*128 bf16
  u16* xb_a = (u16*)(w + o); o += 1280000;
  u16* Wt1 = (u16*)(w + o); o += 81920;              // 1280*128 bf16
  u16* Wt2 = (u16*)(w + o); o += 20480;              // 160*256 bf16
  float* bp1 = w + o; o += 1280;
  float* bp2 = w + o; o += 160;
  float* als = w + o; o += NN * 4;
  float* ald = w + o; o += NN * 4;
  float* x2a = w + o; o += NN * 32;
  int* deg = (int*)(w + o); o += NN;
  int* offs = (int*)(w + o); o += NN + 8;
  int* cur = (int*)(w + o); o += NN;
  int* esrcs = (int*)(w + o); o += NE;
  float* colsum_o = w + o; o += 256;   // 8 shadows x 32
  float* colsum_a = w + o; o += 256;

  float* out = (float*)d_out;
  float* out_log = out;               // [B,2]
  float* out_ret = out + 8192;        // [N,2]
  float* out_reta = out + 48192;      // [N,2]
  float* out_x2o = out + 88192;       // [N,32]
  float* out_logit = out + 728192;    // [1,2N]
  float* out_log1 = out + 768192;     // [B,2]

  // ---- weight packing + input conversion ----
  k_pack1<<<(1280 * 128 + 255) / 256, 256, 0, stream>>>(gat1_w, gt1_wq, gt1_wk, gt1_wv,
                                                        gt1_ws, gt1_bq, gt1_bk, gt1_bv,
                                                        gt1_bs, Wt1, bp1);
  k_pack2<<<(160 * 256 + 255) / 256, 256, 0, stream>>>(gt2_wq, gt2_wk, gt2_wv, gt2_ws,
                                                       gat2_w, gt2_bq, gt2_bk, gt2_bv,
                                                       gt2_bs, Wt2, bp2);
  k_tobf16x2<<<(2 * NN * 128 + 255) / 256, 256, 0, stream>>>(x_o, x_a, xb_o, xb_a);
  // ---- CSR build + colsum zero ----
  hipMemsetAsync(deg, 0, NN * sizeof(int), stream);
  hipMemsetAsync(colsum_o, 0, 512 * sizeof(float), stream);
  k_hist<<<(NE + 255) / 256, 256, 0, stream>>>(edst, deg);
  k_scan20000<<<1, 1024, 0, stream>>>(deg, offs, cur);
  k_scatter<<<(NE + 255) / 256, 256, 0, stream>>>(esrc, edst, cur, esrcs);

  auto branch = [&](const u16* xb, float* x2out, float* colsum) {
    // layer 1: MFMA GEMM (bf16 A) + fused als/ald epilogue
    {
      dim3 g(10, (NN + 127) / 128);
      k_mfma_gemm_s<1><<<g, 256, 0, stream>>>(xb, xb, 999, Wt1, bp1, NN, 128, 1280,
                                              G8, C1b, gat1_asrc, gat1_adst, als, ald);
    }
    k_agg256_fused<<<NN / 2, 256, 0, stream>>>(offs, esrcs, als, ald, G8, C1b,
                                               gat1_b, pg1, pt1, bufB, bufE);
    // layer 2: MFMA GEMM (bf16 A) + fused als/ald epilogue
    {
      dim3 g(2, (NN + 127) / 128);
      k_mfma_gemm_s<2><<<g, 256, 0, stream>>>(bufE, bufB, 1, Wt2, bp2, NN, 256, 160,
                                              G28, C2b, gat2_asrc, gat2_adst, als, ald);
    }
    k_agg32_fuse<<<NN / 8, 256, 0, stream>>>(offs, esrcs, als, ald, G28, C2b,
                                             gat2_b, pg2, pt2, fuse_w, fuse_b,
                                             x2out, colsum);
  };

  branch(xb_o, out_x2o, colsum_o);
  branch(xb_a, x2a, colsum_a);

  // ---- summary + discriminator + adversarial (fused) ----
  k_disc_all<<<(NN + 255) / 256, 256, 0, stream>>>(out_x2o, x2a, colsum_o, colsum_a,
                                                   mlp1_w, mlp1_b, disc_w, disc_b,
                                                   adv_w, adv_b, out_ret, out_reta,
                                                   out_logit);
  // ---- decoder (dec1+dec2 fused) ----
  k_dec<<<NB, 256, 0, stream>>>(out_x2o, idx0, idx1, fus_w1, fus_b1, fus_w2, fus_b2,
                                fus_w3, fus_b3, out_log, out_log1);
}